// Round 2
// baseline (337.158 us; speedup 1.0000x reference)
//
#include <hip/hip_runtime.h>
#include <math.h>

// CSR segmented softmax, round 2: balanced chunk-walk over LDS-staged edges.
//   - one wave owns 64 consecutive nodes; its edge range is contiguous
//   - stage global->LDS coalesced (dwordx4 global side)
//   - each lane walks an EQUAL contiguous chunk of ~range/64 edges (balanced,
//     vs round-1's wave-max-degree serial loops = 4.7x waste)
//   - per-node max/sum via LDS atomics (ds_max_u32 on ordered key, ds_add_f32)
//   - LDS padded +1 float per 32 to break chunk-stride bank conflicts
#define NPW 64                  // nodes per wave
#define WPB 4                   // waves per block
#define BLOCK (64 * WPB)        // 256
#define NPB (NPW * WPB)         // 256 nodes per block
#define CAP 2048                // max staged edges per wave (mean 1024, sigma 128)
#define PCAP (CAP + (CAP >> 5)) // padded floats per wave: 2112

__device__ __forceinline__ int pidx(int j) { return j + (j >> 5); }

// order-preserving float -> uint key (for integer atomicMax)
__device__ __forceinline__ unsigned fkey(float f) {
  unsigned u = __float_as_uint(f);
  return (u & 0x80000000u) ? ~u : (u | 0x80000000u);
}
__device__ __forceinline__ float funkey(unsigned k) {
  return (k & 0x80000000u) ? __uint_as_float(k & 0x7fffffffu)
                           : __uint_as_float(~k);
}

typedef float vf4 __attribute__((ext_vector_type(4), aligned(4)));

struct WaveLds {
  float    ebuf[PCAP];   // padded edge slice
  int      rs[NPW + 2];  // relative row starts [0..64]
  unsigned mkey[NPW];    // per-node max (ordered-key)
  float    ssum[NPW];    // per-node sum -> later 1/sum
};

__global__ __launch_bounds__(BLOCK, 4)
void seg_softmax_kernel(const int* __restrict__ row_ptr,
                        const float* __restrict__ scores,
                        float* __restrict__ out, int n_nodes) {
  __shared__ WaveLds w[WPB];     // ~36.9 KB/block -> 4 blocks/CU
  const int tid = threadIdx.x, wv = tid >> 6, lane = tid & 63;
  WaveLds& L = w[wv];
  const int base = blockIdx.x * NPB + wv * NPW;
  const int i0 = min(base + lane, n_nodes);
  const int i1 = min(base + lane + 1, n_nodes);
  const int ls = row_ptr[i0];
  const int le = row_ptr[i1];
  const int wstart = __shfl(ls, 0);
  const int wend   = __shfl(le, 63);
  const int range  = wend - wstart;

  if (range <= CAP) {
    L.rs[lane] = ls - wstart;
    if (lane == 63) L.rs[64] = range;
    L.mkey[lane] = 0u;           // fkey(-inf) = 0x007FFFFF > 0, safe floor
    L.ssum[lane] = 0.0f;

    // ---- stage: global -> LDS (vector global reads, scalar padded LDS writes)
    {
      const int rv = range & ~3;
      for (int j = 4 * lane; j < rv; j += 4 * 64) {
        vf4 v = *(const vf4*)(scores + wstart + j);
        const int p = pidx(j);   // j%4==0 -> 4-group contiguous in padded space
        L.ebuf[p] = v.x; L.ebuf[p + 1] = v.y;
        L.ebuf[p + 2] = v.z; L.ebuf[p + 3] = v.w;
      }
      for (int j = rv + lane; j < range; j += 64)
        L.ebuf[pidx(j)] = scores[wstart + j];
    }
    __syncthreads();                                   // 1

    // ---- balanced chunk for this lane
    const int chunk = (range + 63) >> 6;
    const int c0 = min(lane * chunk, range);
    const int c1 = min(c0 + chunk, range);
    // starting node: last n with rs[n] <= c0 (upper_bound - 1)
    int n0 = 0;
    {
      int lo = 0, hi = 64;
      while (hi - lo > 1) {
        const int mid = (lo + hi) >> 1;
        if (L.rs[mid] <= c0) lo = mid; else hi = mid;
      }
      n0 = lo;
    }

    // ---- pass A: per-node max (balanced walk + ds_max_u32 flush)
    {
      int j = c0, n = n0;
      while (j < c1) {
        while (L.rs[n + 1] <= j) ++n;                  // skip empty nodes
        const int stop = min(L.rs[n + 1], c1);
        float m = -INFINITY;
        for (; j < stop; ++j) m = fmaxf(m, L.ebuf[pidx(j)]);
        atomicMax(&L.mkey[n], fkey(m));
      }
    }
    __syncthreads();                                   // 2

    // ---- pass B: exp + per-node sum (ds_add_f32 flush)
    {
      int j = c0, n = n0;
      while (j < c1) {
        while (L.rs[n + 1] <= j) ++n;
        const int stop = min(L.rs[n + 1], c1);
        const float m = funkey(L.mkey[n]);
        float s = 0.0f;
        for (; j < stop; ++j) {
          const float e = __expf(L.ebuf[pidx(j)] - m);
          L.ebuf[pidx(j)] = e;
          s += e;
        }
        atomicAdd(&L.ssum[n], s);
      }
    }
    __syncthreads();                                   // 3
    L.ssum[lane] = 1.0f / L.ssum[lane];                // empty node -> inf, unread
    __syncthreads();                                   // 4

    // ---- pass C: scale by 1/sum
    {
      int j = c0, n = n0;
      while (j < c1) {
        while (L.rs[n + 1] <= j) ++n;
        const int stop = min(L.rs[n + 1], c1);
        const float r = L.ssum[n];
        for (; j < stop; ++j) L.ebuf[pidx(j)] *= r;
      }
    }
    __syncthreads();                                   // 5

    // ---- store: LDS -> global coalesced (vector global writes)
    {
      const int rv = range & ~3;
      for (int j = 4 * lane; j < rv; j += 4 * 64) {
        const int p = pidx(j);
        vf4 v;
        v.x = L.ebuf[p]; v.y = L.ebuf[p + 1];
        v.z = L.ebuf[p + 2]; v.w = L.ebuf[p + 3];
        *(vf4*)(out + wstart + j) = v;
      }
      for (int j = rv + lane; j < range; j += 64)
        out[wstart + j] = L.ebuf[pidx(j)];
    }
  } else {
    // fallback (range > CAP): direct-global, ~never taken. 5 barriers to match.
    __syncthreads();
    float m = -INFINITY;
    for (int j = ls; j < le; ++j) m = fmaxf(m, scores[j]);
    __syncthreads();
    float s = 0.0f;
    for (int j = ls; j < le; ++j) {
      const float e = __expf(scores[j] - m);
      s += e;
      out[j] = e;
    }
    __syncthreads();
    const float r = 1.0f / s;
    __syncthreads();
    for (int j = ls; j < le; ++j) out[j] *= r;
    __syncthreads();
  }
}

extern "C" void kernel_launch(void* const* d_in, const int* in_sizes, int n_in,
                              void* d_out, int out_size, void* d_ws, size_t ws_size,
                              hipStream_t stream) {
  const int*   row_ptr = (const int*)d_in[0];
  const float* scores  = (const float*)d_in[1];
  float*       out     = (float*)d_out;
  const int n_nodes = in_sizes[0] - 1;
  const int blocks  = (n_nodes + NPB - 1) / NPB;
  seg_softmax_kernel<<<blocks, BLOCK, 0, stream>>>(row_ptr, scores, out, n_nodes);
}

// Round 3
// 242.346 us; speedup vs baseline: 1.3912x; 1.3912x over previous
//
#include <hip/hip_runtime.h>
#include <math.h>

// CSR segmented softmax, round 3: wave-per-block, register-resident edges.
//   - one 64-lane wave per block owns 64 consecutive nodes (contiguous edges)
//   - phase 1: strided global->reg load, WAVE max (valid shift: constant per
//     node), exp in regs, ds_write_b128 of e to LDS. No ragged max pass.
//   - phase 2: lane-per-node sum from LDS (paired b64 reads, simple
//     pipelinable loop — NO branches on loaded values; round-2 lesson)
//   - phase 3: lane writes its node id into nbuf, word-packed (deg/4 ops)
//   - phase 4: strided store: e from REGISTERS * rpn[nbuf[j]] -> global
// LDS ops/wave ~0.6K cyc vs round-1's ~2.4K. 10.5 KB/block -> 15 blocks/CU.
#define NPW 64
#define BLOCK 64
#define CAP 2048          // max edges per wave (round-2-proven: never exceeded)
#define MAXG (CAP / 256)  // 8 groups of 4 floats per lane

struct __align__(16) WaveLds {
  float         ebuf[CAP];   // exp values (b128-written)
  unsigned char nbuf[CAP];   // per-edge relative node id
  float         rpn[NPW];    // per-node 1/sum
};

__global__ __launch_bounds__(BLOCK, 4)
void seg_softmax_kernel(const int* __restrict__ row_ptr,
                        const float* __restrict__ scores,
                        float* __restrict__ out, int n_nodes) {
  __shared__ WaveLds L;      // 10496 B -> 15 blocks/CU
  const int lane = threadIdx.x;
  const int base = blockIdx.x * NPW;
  const int i0 = min(base + lane, n_nodes);
  const int i1 = min(base + lane + 1, n_nodes);
  const int ls = row_ptr[i0];
  const int le = row_ptr[i1];
  const int wstart = __shfl(ls, 0);
  const int wend   = __shfl(le, 63);
  const int range  = wend - wstart;

  if (range <= CAP) {
    const int a = ls - wstart, b = le - wstart;

    // ---- phase 1: global -> regs (strided, coalesced), wave max, exp, -> LDS
    float v[4 * MAXG];
    #pragma unroll
    for (int g = 0; g < MAXG; ++g) {
      const int j0 = 4 * lane + 256 * g;
      if (j0 + 4 <= range) {
        #pragma unroll
        for (int k = 0; k < 4; ++k) v[4 * g + k] = scores[wstart + j0 + k];
      } else {
        #pragma unroll
        for (int k = 0; k < 4; ++k)
          v[4 * g + k] = (j0 + k < range) ? scores[wstart + j0 + k] : -INFINITY;
      }
    }
    float m = v[0];
    #pragma unroll
    for (int i = 1; i < 4 * MAXG; ++i) m = fmaxf(m, v[i]);
    #pragma unroll
    for (int off = 32; off >= 1; off >>= 1) m = fmaxf(m, __shfl_xor(m, off));
    // range>0 -> m finite; exp(-inf - m) = 0 for padding lanes.
    #pragma unroll
    for (int i = 0; i < 4 * MAXG; ++i) v[i] = __expf(v[i] - m);
    #pragma unroll
    for (int g = 0; g < MAXG; ++g) {
      const int j0 = 4 * lane + 256 * g;
      if (j0 + 4 <= range) {
        float4 q = make_float4(v[4 * g], v[4 * g + 1], v[4 * g + 2], v[4 * g + 3]);
        *(float4*)&L.ebuf[j0] = q;                 // 16B-aligned -> ds_write_b128
      } else if (j0 < range) {
        #pragma unroll
        for (int k = 0; k < 4; ++k)
          if (j0 + k < range) L.ebuf[j0 + k] = v[4 * g + k];
      }
    }
    __syncthreads();

    // ---- phase 2: per-node sum (own segment, paired reads, no loaded-branch)
    float s = 0.0f;
    {
      int j = a;
      if ((j & 1) && j < b) { s += L.ebuf[j]; ++j; }
      float s2 = 0.0f;
      for (; j + 1 < b; j += 2) {
        const float2 p = *(const float2*)&L.ebuf[j];   // 8B-aligned
        s += p.x; s2 += p.y;
      }
      if (j < b) s += L.ebuf[j];
      s += s2;
    }
    L.rpn[lane] = 1.0f / s;        // empty node -> inf, never read back

    // ---- phase 3: per-edge node id, word-packed writes (deg/4 + 2 ops)
    {
      const unsigned wq = (unsigned)lane * 0x01010101u;
      int j = a;
      while (j < b && (j & 3)) { L.nbuf[j] = (unsigned char)lane; ++j; }
      for (; j + 4 <= b; j += 4) *(unsigned*)&L.nbuf[j] = wq;
      for (; j < b; ++j) L.nbuf[j] = (unsigned char)lane;
    }
    __syncthreads();

    // ---- phase 4: out[j] = e(regs) * rpn[nbuf[j]], coalesced store
    #pragma unroll
    for (int g = 0; g < MAXG; ++g) {
      const int j0 = 4 * lane + 256 * g;
      if (j0 + 4 <= range) {
        const unsigned ids = *(const unsigned*)&L.nbuf[j0];
        out[wstart + j0 + 0] = v[4 * g + 0] * L.rpn[ids & 255u];
        out[wstart + j0 + 1] = v[4 * g + 1] * L.rpn[(ids >> 8) & 255u];
        out[wstart + j0 + 2] = v[4 * g + 2] * L.rpn[(ids >> 16) & 255u];
        out[wstart + j0 + 3] = v[4 * g + 3] * L.rpn[ids >> 24];
      } else if (j0 < range) {
        #pragma unroll
        for (int k = 0; k < 4; ++k)
          if (j0 + k < range)
            out[wstart + j0 + k] = v[4 * g + k] * L.rpn[L.nbuf[j0 + k]];
      }
    }
  } else {
    // fallback (range > CAP): direct-global, never taken on this data.
    // Single-wave block + wave-uniform branch -> no barrier-matching hazard.
    float m = -INFINITY;
    for (int j = ls; j < le; ++j) m = fmaxf(m, scores[j]);
    float s = 0.0f;
    for (int j = ls; j < le; ++j) {
      const float e = __expf(scores[j] - m);
      s += e;
      out[j] = e;
    }
    const float r = 1.0f / s;
    for (int j = ls; j < le; ++j) out[j] *= r;
  }
}

extern "C" void kernel_launch(void* const* d_in, const int* in_sizes, int n_in,
                              void* d_out, int out_size, void* d_ws, size_t ws_size,
                              hipStream_t stream) {
  const int*   row_ptr = (const int*)d_in[0];
  const float* scores  = (const float*)d_in[1];
  float*       out     = (float*)d_out;
  const int n_nodes = in_sizes[0] - 1;
  const int blocks  = (n_nodes + NPW - 1) / NPW;
  seg_softmax_kernel<<<blocks, BLOCK, 0, stream>>>(row_ptr, scores, out, n_nodes);
}